// Round 1
// baseline (489.140 us; speedup 1.0000x reference)
//
#include <hip/hip_runtime.h>

// Multi-step integrate-and-fire (T=16 scan), x_seq: (16,32,128,32,32) fp32.
// Memory-bound streaming: ~268 MB in + ~268 MB out per launch.
//
// R1: NT stores for output (keep input hot in L3) -- kept.
// R3: rocprof showed 2.5 TB/s @ 173us, VALUBusy 3.5%, VGPR=28.
//     Diagnosis: latency-bound, not BW-bound. Loop-carried structure let the
//     compiler allocate 28 VGPRs and reuse the load registers each t-step ->
//     ~1 load-pair in flight per wave, waitcnt stall every iteration.
//     Fix: loads are independent of the serial v-chain, so preload ALL 16
//     t-slices per thread into registers (16 outstanding global_load_dwordx4,
//     64 VGPRs of payload), then run the scan and NT-store 16 results.
//     Predicted: dur ~95-115us, ~4+ TB/s, VGPR ~80-100.

#define T_STEPS 16

typedef float f32x4 __attribute__((ext_vector_type(4)));

__global__ __launch_bounds__(256) void if_scan_kernel(
    const f32x4* __restrict__ x, f32x4* __restrict__ out, int n4) {
    int i = blockIdx.x * blockDim.x + threadIdx.x;
    if (i >= n4) return;

    // 16 independent loads, issued back-to-back: 16 KB in flight per wave.
    f32x4 xv[T_STEPS];
#pragma unroll
    for (int t = 0; t < T_STEPS; ++t) {
        xv[t] = x[(size_t)t * (size_t)n4 + (size_t)i];
    }

    // Serial scan is pure VALU (add/cmp/sub), drains vmcnt incrementally.
    f32x4 v = (f32x4)(0.f);
#pragma unroll
    for (int t = 0; t < T_STEPS; ++t) {
        v += xv[t];
        f32x4 s;
        s.x = (v.x >= 1.0f) ? 1.0f : 0.0f;
        s.y = (v.y >= 1.0f) ? 1.0f : 0.0f;
        s.z = (v.z >= 1.0f) ? 1.0f : 0.0f;
        s.w = (v.w >= 1.0f) ? 1.0f : 0.0f;
        v -= s;
        __builtin_nontemporal_store(s, &out[(size_t)t * (size_t)n4 + (size_t)i]);
    }
}

extern "C" void kernel_launch(void* const* d_in, const int* in_sizes, int n_in,
                              void* d_out, int out_size, void* d_ws, size_t ws_size,
                              hipStream_t stream) {
    const float* x = (const float*)d_in[0];
    float* out = (float*)d_out;

    int total = in_sizes[0];             // 16*32*128*32*32 = 67108864
    int per_step = total / T_STEPS;      // 4194304 floats per timestep
    int n4 = per_step / 4;               // 1048576 float4 per timestep

    dim3 block(256);
    dim3 grid((n4 + block.x - 1) / block.x);   // 4096 blocks
    if_scan_kernel<<<grid, block, 0, stream>>>(
        (const f32x4*)x, (f32x4*)out, n4);
}